// Round 7
// baseline (14606.561 us; speedup 1.0000x reference)
//
#include <hip/hip_runtime.h>
#include <stdint.h>

#define NU 4096
#define NB 2048
#define KK2 8192
#define ITERS 100
#define CAP 262144
#define THETA 0.05f
#define KC 512              // host fixup k-panel (verified)

// ws layout (bytes) — unchanged
#define OFF_BT   0u
#define OFF_A0   67108864u
#define OFF_A1   83886080u
#define OFF_SUS  100663296u
#define OFF_CNT  102760448u
#define REQ_WS   102761472u

// GEMM geometry: BM=128 x BN=128, 256 thr (4 waves 2Mx2N, wave-tile 64x64),
// grid 16x32=512 blocks -> EXACTLY 2 blocks/CU (the round-7 lever: two
// independent barrier domains per CU so one block's vmcnt/barrier windows
// are filled by the other block's MFMAs; R1/R4/R6 showed intra-block
// scheduling is ceiling'd at ~31% MfmaUtil with 1 lockstep block/CU).
// BK=32, 128 K-tiles; per tile cluster hi (af x Bhi) + lo (af x Blo), A
// fragments reused across the W_hi/W_lo split. 3-slab LDS rotation,
// 24 KB/slab (A 8K @+0, Bhi 8K @+8192, Blo 8K @+16384) = 72 KB/block;
// 2 blocks/CU = 144 KB <= 160 KB. Tile k: compute k (slab s0), prime k+1
// (slab s1, staged during k-1 -> published one barrier ago), stage k+2
// (slab s2). vmcnt(0) per tile: retires the batch issued at THIS tile's
// start (~1 tile body issue distance); residual stalls are cross-block
// filled. SLOT SWIZZLE (round-6, measured 0 conflicts): logical 16B slot
// sl of row r at phys slot (sl+(r>>1))&3; global source col carries the
// inverse; ds_read uses pslot=(lk+((lm>>1)&3))&3. All staging row terms
// are == 0 mod 8 in the new geometry, so the congruences carry unchanged.
#define NT 128

typedef float f32x4 __attribute__((ext_vector_type(4)));
typedef __bf16 bf16x8 __attribute__((ext_vector_type(8)));

__device__ __forceinline__ unsigned short f2bf(float x) {
  unsigned u = __float_as_uint(x);
  u += 0x7FFFu + ((u >> 16) & 1u);
  return (unsigned short)(u >> 16);
}
__device__ __forceinline__ float bf2f(unsigned short h) {
  return __uint_as_float(((unsigned)h) << 16);
}

__device__ __forceinline__ void gl16(const unsigned short* g, char* l) {
  __builtin_amdgcn_global_load_lds(
      (const __attribute__((address_space(1))) unsigned int*)g,
      (__attribute__((address_space(3))) unsigned int*)l, 16, 0, 0);
}

__global__ void fill_kernel(float* __restrict__ out, float v) {
  int t = blockIdx.x * blockDim.x + threadIdx.x;
  int base = t << 3;
  float4 a = make_float4(v, v, v, v);
  *(float4*)(out + base) = a;
  *(float4*)(out + base + 4) = a;
}

__global__ void decompose_kernel(const float* __restrict__ W,
                                 unsigned short* __restrict__ Bt) {
  int t = blockIdx.x * blockDim.x + threadIdx.x;
  int base = t << 2;
  int j = base >> 12;
  int k = base & 4095;
  float4 w = *(const float4*)(W + (size_t)j * NU + k);
  unsigned short h0 = f2bf(w.x), h1 = f2bf(w.y), h2 = f2bf(w.z), h3 = f2bf(w.w);
  ushort4 hi = make_ushort4(h0, h1, h2, h3);
  ushort4 lo = make_ushort4(f2bf(w.x - bf2f(h0)), f2bf(w.y - bf2f(h1)),
                            f2bf(w.z - bf2f(h2)), f2bf(w.w - bf2f(h3)));
  *(ushort4*)(Bt + (size_t)j * KK2 + k) = hi;
  *(ushort4*)(Bt + (size_t)j * KK2 + NU + k) = lo;
}

// Initial state: P (fp32 +-1, exact) -> A0 bf16 +-1.
__global__ void init_kernel(const float* __restrict__ P,
                            unsigned short* __restrict__ A0) {
  int t = blockIdx.x * blockDim.x + threadIdx.x;
  int base = t << 3;
  float4 a = *(const float4*)(P + base);
  float4 b = *(const float4*)(P + base + 4);
  float hv[8] = {a.x, a.y, a.z, a.w, b.x, b.y, b.z, b.w};
  uint4 pk;
  unsigned short s[8];
#pragma unroll
  for (int i = 0; i < 8; ++i)
    s[i] = (hv[i] >= 0.0f) ? (unsigned short)0x3F80u : (unsigned short)0xBF80u;
  pk.x = (unsigned)s[0] | ((unsigned)s[1] << 16);
  pk.y = (unsigned)s[2] | ((unsigned)s[3] << 16);
  pk.z = (unsigned)s[4] | ((unsigned)s[5] << 16);
  pk.w = (unsigned)s[6] | ((unsigned)s[7] << 16);
  *(uint4*)(A0 + base) = pk;
}

// ---- schedule primitives ----
#define SCB() __builtin_amdgcn_sched_barrier(0)
#define BAR() do { __builtin_amdgcn_sched_barrier(0);          \
                   __builtin_amdgcn_s_barrier();               \
                   __builtin_amdgcn_sched_barrier(0); } while (0)
#define VM0() do { asm volatile("s_waitcnt vmcnt(0)" ::: "memory");    \
                   __builtin_amdgcn_sched_barrier(0); } while (0)
#define MM(AF, BF) do { __builtin_amdgcn_s_setprio(1);                       \
  _Pragma("unroll") for (int i_ = 0; i_ < 4; ++i_)                           \
  _Pragma("unroll") for (int j_ = 0; j_ < 4; ++j_)                           \
    acc[i_][j_] = __builtin_amdgcn_mfma_f32_16x16x32_bf16(                   \
        AF[i_], BF[j_], acc[i_][j_], 0, 0, 0);                               \
  __builtin_amdgcn_s_setprio(0); } while (0)
#define RD4S(DST, BASE) _Pragma("unroll")                                     \
  for (int q_ = 0; q_ < 4; ++q_)                                              \
    DST[q_] = *(const bf16x8*)((BASE) + q_ * 1024);

// One K-tile body with rotating slabs: s0 = compute (tile k), s1 = prime
// source (tile k+1), s2 = stage dest (tile k+2). CF* primed during k-1.
// Slab hazard: slab j's primes run during tile j-1 and retire via compiler
// lgkm-waits before tile j-1's last MFMAs -> before the j-1 -> j barrier;
// slab j is rewritten during tile j+... (stage of j+3's content lands 3
// rotations later) — always >= 1 publishing barrier after last read.
// Guards depend only on k (block-uniform).
#define TB(k, CFa, CFh, CFl, PFa, PFh, PFl)                                   \
  {                                                                           \
    const int kS_ = ((k) + 2) << 5;                                           \
    if ((k) + 2 < NT) {                                                       \
      gl16(pAs + kS_, s2 + ldsO);                                             \
      gl16(pAs2 + kS_, s2 + ldsO + 1024);                                     \
      gl16(pBsH + kS_, s2 + 8192 + ldsO);                                     \
      gl16(pBsH2 + kS_, s2 + 8192 + ldsO + 1024);                             \
      gl16(pBsL + kS_, s2 + 16384 + ldsO);                                    \
      gl16(pBsL2 + kS_, s2 + 16384 + ldsO + 1024);                            \
    }                                                                         \
    SCB();                                                                    \
    MM(CFa, CFh);                                                             \
    SCB();                                                                    \
    if ((k) + 1 < NT) {                                                       \
      RD4S(PFa, s1 + aOff);                                                   \
      RD4S(PFh, s1 + 8192 + bOff);                                            \
    }                                                                         \
    SCB();                                                                    \
    MM(CFa, CFl);                                                             \
    SCB();                                                                    \
    if ((k) + 1 < NT) { RD4S(PFl, s1 + 16384 + bOff); }                       \
    SCB();                                                                    \
    VM0();                                                                    \
    BAR();                                                                    \
    char* r_ = s0; s0 = s1; s1 = s2; s2 = r_;                                 \
  }

__global__ void __launch_bounds__(256, 2)
gemm_fused_kernel(const unsigned short* __restrict__ A,
                  const unsigned short* __restrict__ Bt,
                  unsigned short* __restrict__ Anext,
                  float* __restrict__ outF, int writeOut,
                  int* __restrict__ counter,
                  int* __restrict__ suspects) {
  __shared__ __align__(16) unsigned short sL[36864];   // 73728 B = 3 x 24KB
  const int tid = threadIdx.x;
  const int wave = tid >> 6, lane = tid & 63;
  const int lm = lane & 15, lk = lane >> 4;
  const int wm = wave >> 1, wn = wave & 1;             // 2M x 2N wave grid
  const int nt = blockIdx.x & 31, mt = blockIdx.x >> 5;
  const int mBase = mt << 7, nBase = nt << 7;

  // ---- staging lane constants ----
  // LDS dest linear (wave base + lane*16). Global source col carries the
  // inverse slot swizzle: cs = ((lane&3)-((lane>>3)&3))&3 slots of 8 elems.
  // Rows r = {m/n}Base + wave*32 + rl + {0,16}: all terms == 0 mod 8 except
  // rl -> (r>>1)&3 == (lane>>3)&3, identical to the verified round-6 form.
  const int rl = lane >> 2;                            // 0..15 rows
  const int cs = ((((lane & 3) - ((lane >> 3) & 3)) & 3) << 3);  // elems
  const unsigned short* pAs = A + (size_t)(mBase + (wave << 5) + rl) * NU + cs;
  const unsigned short* pAs2 = pAs + (size_t)16 * NU;
  const unsigned short* pBsH = Bt + (size_t)(nBase + (wave << 5) + rl) * KK2 + cs;
  const unsigned short* pBsH2 = pBsH + (size_t)16 * KK2;
  const unsigned short* pBsL = pBsH + NU;
  const unsigned short* pBsL2 = pBsH2 + NU;
  const int ldsO = wave << 11;                         // wave*2048 B
  char* s0 = (char*)sL;                                // compute slab
  char* s1 = s0 + 24576;                               // prime slab
  char* s2 = s0 + 49152;                               // stage slab

  // ---- fragment-read lane constants ----
  // phys slot = (lk + (row>>1))&3; row = {wm,wn}*64 + q*16 + lm ->
  // (row>>1)&3 == (lm>>1)&3 (other terms == 0 mod 4 after >>1).
  const int pslot = (lk + ((lm >> 1) & 3)) & 3;
  const int aOff = (((wm << 6) + lm) << 6) + (pslot << 4);
  const int bOff = (((wn << 6) + lm) << 6) + (pslot << 4);

  f32x4 acc[4][4] = {};
  bf16x8 afA[4], bhA[4], blA[4], afB[4], bhB[4], blB[4];

  // prologue: stage tile 0 -> s0, tile 1 -> s1; publish; prime tile 0 (set A)
  gl16(pAs, s0 + ldsO);           gl16(pAs2, s0 + ldsO + 1024);
  gl16(pBsH, s0 + 8192 + ldsO);   gl16(pBsH2, s0 + 8192 + ldsO + 1024);
  gl16(pBsL, s0 + 16384 + ldsO);  gl16(pBsL2, s0 + 16384 + ldsO + 1024);
  gl16(pAs + 32, s1 + ldsO);          gl16(pAs2 + 32, s1 + ldsO + 1024);
  gl16(pBsH + 32, s1 + 8192 + ldsO);  gl16(pBsH2 + 32, s1 + 8192 + ldsO + 1024);
  gl16(pBsL + 32, s1 + 16384 + ldsO); gl16(pBsL2 + 32, s1 + 16384 + ldsO + 1024);
  VM0();
  BAR();
  RD4S(afA, s0 + aOff);
  RD4S(bhA, s0 + 8192 + bOff);
  RD4S(blA, s0 + 16384 + bOff);

  for (int k = 0; k < NT; k += 2) {
    TB(k, afA, bhA, blA, afB, bhB, blB);
    TB(k + 1, afB, bhB, blB, afA, bhA, blA);
  }

  // Fused sign epilogue. C/D layout (m89/m91): col=lane&15, row=(lane>>4)*4+reg
#pragma unroll
  for (int i = 0; i < 4; ++i)
#pragma unroll
    for (int j = 0; j < 4; ++j)
#pragma unroll
      for (int r = 0; r < 4; ++r) {
        const int row = mBase + (wm << 6) + i * 16 + (lk << 2) + r;
        const int col = nBase + (wn << 6) + j * 16 + lm;
        const float h = acc[i][j][r];
        Anext[(size_t)row * NU + col] =
            (h >= 0.0f) ? (unsigned short)0x3F80u : (unsigned short)0xBF80u;
        if (fabsf(h) < THETA) {
          int idx = atomicAdd(counter, 1);
          if (idx < CAP) suspects[idx] = (row << 12) | col;
        }
        if (writeOut)
          outF[(size_t)row * NU + col] = (h >= 0.0f) ? 1.0f : -1.0f;
      }
}

// Suspects, 8 lanes per suspect (one per KC=512 panel). Same sequential fp32
// chain as the round-8-verified version; bitwise-identical sign decision.
__global__ void fixup_kernel(const unsigned short* __restrict__ Acur,
                             const float* __restrict__ W,
                             unsigned short* __restrict__ Anext,
                             float* __restrict__ outF, int writeOut,
                             const int* __restrict__ counter,
                             const int* __restrict__ suspects,
                             int* __restrict__ flagOv) {
  int n = *counter;
  if (blockIdx.x == 0 && threadIdx.x == 0 && n > CAP) atomicAdd(flagOv, 1);
  n = n < CAP ? n : CAP;
  const int lane = threadIdx.x & 7;                       // panel index
  const int gid = (blockIdx.x * blockDim.x + threadIdx.x) >> 3;
  const int ngrp = (gridDim.x * blockDim.x) >> 3;
  for (int i = gid; i < n; i += ngrp) {
    int idx = suspects[i];
    int b = idx >> 12, j = idx & 4095;
    const float* wrow = W + (size_t)j * NU + lane * KC;
    const unsigned short* arow = Acur + (size_t)b * NU + lane * KC;
    float part = 0.0f;
    for (int k = 0; k < KC; k += 4) {
      float4 wv = *(const float4*)(wrow + k);
      ushort4 av = *(const ushort4*)(arow + k);
      part += (av.x & 0x8000) ? -wv.x : wv.x;
      part += (av.y & 0x8000) ? -wv.y : wv.y;
      part += (av.z & 0x8000) ? -wv.z : wv.z;
      part += (av.w & 0x8000) ? -wv.w : wv.w;
    }
    float c = __shfl(part, 0, 8);
#pragma unroll
    for (int q = 1; q < 8; ++q) c += __shfl(part, q, 8);
    if (lane == 0) {
      Anext[(size_t)b * NU + j] =
          (c >= 0.0f) ? (unsigned short)0x3F80u : (unsigned short)0xBF80u;
      if (writeOut) outF[(size_t)b * NU + j] = (c >= 0.0f) ? 1.0f : -1.0f;
    }
  }
}

// Tripwire: if the suspect list ever overflows, poison the output signature.
__global__ void assemble_kernel(float* __restrict__ out,
                                const int* __restrict__ flags) {
  if (threadIdx.x != 0 || blockIdx.x != 0) return;
  if (flags[1]) out[0] = 7777.0f;
}

extern "C" void kernel_launch(void* const* d_in, const int* in_sizes, int n_in,
                              void* d_out, int out_size, void* d_ws, size_t ws_size,
                              hipStream_t stream) {
  const float* P = (const float*)d_in[0];
  const float* W = (const float*)d_in[1];
  float* out = (float*)d_out;

  if (n_in < 2 || in_sizes[0] != NB * NU || in_sizes[1] != NU * NU ||
      out_size != NB * NU) {
    fill_kernel<<<4096, 256, 0, stream>>>(out, 9.0f);
    return;
  }
  if (ws_size < (size_t)REQ_WS) {
    fill_kernel<<<4096, 256, 0, stream>>>(out, 3.0f);
    return;
  }

  char* w = (char*)d_ws;
  unsigned short* Bt = (unsigned short*)(w + OFF_BT);
  unsigned short* A0 = (unsigned short*)(w + OFF_A0);
  unsigned short* A1 = (unsigned short*)(w + OFF_A1);
  int* suspects = (int*)(w + OFF_SUS);
  int* counters = (int*)(w + OFF_CNT);
  int* flags = counters + 128;  // [1]=suspect overflow

  hipMemsetAsync(counters, 0, 1024, stream);
  decompose_kernel<<<16384, 256, 0, stream>>>(W, Bt);
  init_kernel<<<4096, 256, 0, stream>>>(P, A0);

  for (int t = 0; t < ITERS; ++t) {
    unsigned short* Ain = (t & 1) ? A1 : A0;
    unsigned short* Aout = (t & 1) ? A0 : A1;
    int fin = (t == ITERS - 1) ? 1 : 0;
    gemm_fused_kernel<<<512, 256, 0, stream>>>(Ain, Bt, Aout, out, fin,
                                               &counters[t], suspects);
    fixup_kernel<<<256, 256, 0, stream>>>(Ain, W, Aout, out, fin,
                                          &counters[t], suspects, &flags[1]);
  }
  assemble_kernel<<<1, 64, 0, stream>>>(out, flags);
}

// Round 8
// 14195.316 us; speedup vs baseline: 1.0290x; 1.0290x over previous
//
#include <hip/hip_runtime.h>
#include <stdint.h>

#define NU 4096
#define NB 2048
#define KK2 8192
#define ITERS 100
#define CAP 262144
#define THETA 0.05f
#define KC 512              // host fixup k-panel (verified)

// ws layout (bytes) — unchanged
#define OFF_BT   0u
#define OFF_A0   67108864u
#define OFF_A1   83886080u
#define OFF_SUS  100663296u
#define OFF_CNT  102760448u
#define REQ_WS   102761472u

// GEMM geometry: BM=256 x BN=128, 512 thr (8 waves 4Mx2N, wave-tile 64x64),
// grid 8x32 = 256 blocks = 1/CU. BK=32, 128 iters; per iter cluster hi
// (af x Bhi) + lo (af x Blo) — A staged & read once (traffic-optimal tile:
// minimizes 1/BN + 2/BM at BM*BN = 32768).
// m201 PHASE DISCIPLINE (round-8): per phase, ds_reads issue PRE-barrier,
// lgkmcnt(0) POST-barrier, MFMA consumes IN-phase — each wave's LDS batch
// drains while faster waves run MFMAs; barriers every ~250 cyc. 4 slabs x
// 32 KB (A 16K @0, Bh 8K @16384, Bl 8K @24576); stage 3 iters ahead,
// COUNTED vmcnt(8) at iter end (retires batch k+1, issued 2 iters ago).
// SLOT SWIZZLE (round-6, measured 0 conflicts): logical 16B slot sl of row
// r at phys slot (sl+(r>>1))&3; inverse on global source col; ds_read uses
// pslot=(lk+((lm>>1)&3))&3. Congruences identical to R6 (re-derived).
#define NT 128

typedef float f32x4 __attribute__((ext_vector_type(4)));
typedef __bf16 bf16x8 __attribute__((ext_vector_type(8)));

__device__ __forceinline__ unsigned short f2bf(float x) {
  unsigned u = __float_as_uint(x);
  u += 0x7FFFu + ((u >> 16) & 1u);
  return (unsigned short)(u >> 16);
}
__device__ __forceinline__ float bf2f(unsigned short h) {
  return __uint_as_float(((unsigned)h) << 16);
}

__device__ __forceinline__ void gl16(const unsigned short* g, char* l) {
  __builtin_amdgcn_global_load_lds(
      (const __attribute__((address_space(1))) unsigned int*)g,
      (__attribute__((address_space(3))) unsigned int*)l, 16, 0, 0);
}

__global__ void fill_kernel(float* __restrict__ out, float v) {
  int t = blockIdx.x * blockDim.x + threadIdx.x;
  int base = t << 3;
  float4 a = make_float4(v, v, v, v);
  *(float4*)(out + base) = a;
  *(float4*)(out + base + 4) = a;
}

__global__ void decompose_kernel(const float* __restrict__ W,
                                 unsigned short* __restrict__ Bt) {
  int t = blockIdx.x * blockDim.x + threadIdx.x;
  int base = t << 2;
  int j = base >> 12;
  int k = base & 4095;
  float4 w = *(const float4*)(W + (size_t)j * NU + k);
  unsigned short h0 = f2bf(w.x), h1 = f2bf(w.y), h2 = f2bf(w.z), h3 = f2bf(w.w);
  ushort4 hi = make_ushort4(h0, h1, h2, h3);
  ushort4 lo = make_ushort4(f2bf(w.x - bf2f(h0)), f2bf(w.y - bf2f(h1)),
                            f2bf(w.z - bf2f(h2)), f2bf(w.w - bf2f(h3)));
  *(ushort4*)(Bt + (size_t)j * KK2 + k) = hi;
  *(ushort4*)(Bt + (size_t)j * KK2 + NU + k) = lo;
}

// Initial state: P (fp32 +-1, exact) -> A0 bf16 +-1.
__global__ void init_kernel(const float* __restrict__ P,
                            unsigned short* __restrict__ A0) {
  int t = blockIdx.x * blockDim.x + threadIdx.x;
  int base = t << 3;
  float4 a = *(const float4*)(P + base);
  float4 b = *(const float4*)(P + base + 4);
  float hv[8] = {a.x, a.y, a.z, a.w, b.x, b.y, b.z, b.w};
  uint4 pk;
  unsigned short s[8];
#pragma unroll
  for (int i = 0; i < 8; ++i)
    s[i] = (hv[i] >= 0.0f) ? (unsigned short)0x3F80u : (unsigned short)0xBF80u;
  pk.x = (unsigned)s[0] | ((unsigned)s[1] << 16);
  pk.y = (unsigned)s[2] | ((unsigned)s[3] << 16);
  pk.z = (unsigned)s[4] | ((unsigned)s[5] << 16);
  pk.w = (unsigned)s[6] | ((unsigned)s[7] << 16);
  *(uint4*)(A0 + base) = pk;
}

// ---- schedule primitives ----
#define SCB() __builtin_amdgcn_sched_barrier(0)
#define BAR() do { __builtin_amdgcn_sched_barrier(0);          \
                   __builtin_amdgcn_s_barrier();               \
                   __builtin_amdgcn_sched_barrier(0); } while (0)
#define LGK0() do { asm volatile("s_waitcnt lgkmcnt(0)" ::: "memory"); \
                    __builtin_amdgcn_sched_barrier(0); } while (0)
#define VMW(N) do { asm volatile("s_waitcnt vmcnt(" #N ")" ::: "memory"); \
                    __builtin_amdgcn_sched_barrier(0); } while (0)
#define MM(AF, BF) do { __builtin_amdgcn_s_setprio(1);                       \
  _Pragma("unroll") for (int i_ = 0; i_ < 4; ++i_)                           \
  _Pragma("unroll") for (int j_ = 0; j_ < 4; ++j_)                           \
    acc[i_][j_] = __builtin_amdgcn_mfma_f32_16x16x32_bf16(                   \
        AF[i_], BF[j_], acc[i_][j_], 0, 0, 0);                               \
  __builtin_amdgcn_s_setprio(0); } while (0)
#define RD4S(DST, BASE) _Pragma("unroll")                                     \
  for (int q_ = 0; q_ < 4; ++q_)                                              \
    DST[q_] = *(const bf16x8*)((BASE) + q_ * 1024);

// One iter (BK=32), m201 discipline. sC = compute slab (k&3), sS = stage
// dest slab ((k+3)&3). Phase 0: {read af+bh | stage A(k+3)} BAR lgkm0
// MM(af,bh) BAR. Phase 1: {read bl | stage B(k+3)} BAR lgkm0 MM(af,bl)
// vmcnt BAR.
// vmcnt ledger (4 gl16/wave/iter): end of iter k outstanding = batches
// k+1,k+2,k+3 (12) -> vmcnt(8) retires k+1 (issued iter k-2, ~2100 cyc ago),
// published by this BAR, read during iter k+1. k=0,1: <=8 outstanding,
// vmcnt(8) no-op, slabs 1,2 published by prologue. Tail: k=NT-3 -> vmcnt(4)
// retires batch NT-2; k>=NT-2 -> vmcnt(0). Slab hazard: slab j's reads
// retire at iter-j lgkm0 (pre-BAR); restaged during iter j+1 (post-BAR).
// Guards depend only on k (block-uniform).
#define IT(k, sC, sS)                                                         \
  {                                                                           \
    const int kS_ = ((k) + 3) << 5;                                           \
    RD4S(af, (sC) + aOff);                                                    \
    RD4S(bh, (sC) + 16384 + bOff);                                            \
    if ((k) + 3 < NT) {                                                       \
      gl16(pAs + kS_, (sS) + ldsA);                                           \
      gl16(pAs2 + kS_, (sS) + ldsA + 1024);                                   \
    }                                                                         \
    BAR(); LGK0();                                                            \
    MM(af, bh);                                                               \
    BAR();                                                                    \
    RD4S(bl, (sC) + 24576 + bOff);                                            \
    if ((k) + 3 < NT) {                                                       \
      gl16(pBsH + kS_, (sS) + 16384 + ldsB);                                  \
      gl16(pBsL + kS_, (sS) + 24576 + ldsB);                                  \
    }                                                                         \
    BAR(); LGK0();                                                            \
    MM(af, bl);                                                               \
    if ((k) < NT - 3) { VMW(8); }                                             \
    else if ((k) == NT - 3) { VMW(4); }                                       \
    else { VMW(0); }                                                          \
    BAR();                                                                    \
  }

__global__ void __launch_bounds__(512, 1)
gemm_fused_kernel(const unsigned short* __restrict__ A,
                  const unsigned short* __restrict__ Bt,
                  unsigned short* __restrict__ Anext,
                  float* __restrict__ outF, int writeOut,
                  int* __restrict__ counter,
                  int* __restrict__ suspects) {
  __shared__ __align__(16) unsigned short sL[65536];   // 131072 B = 4 x 32KB
  const int tid = threadIdx.x;
  const int wave = tid >> 6, lane = tid & 63;
  const int lm = lane & 15, lk = lane >> 4;
  const int wm = wave >> 1, wn = wave & 1;             // 4M x 2N wave grid
  const int nt = blockIdx.x & 31, mt = blockIdx.x >> 5;
  const int mBase = mt << 8, nBase = nt << 7;

  // ---- staging lane constants (R6-identical; measured 0 conflicts) ----
  const int rl = lane >> 2;                            // 0..15 rows
  const int cs = ((((lane & 3) - ((lane >> 3) & 3)) & 3) << 3);  // elems
  const unsigned short* pAs = A + (size_t)(mBase + (wave << 5) + rl) * NU + cs;
  const unsigned short* pAs2 = pAs + (size_t)16 * NU;
  const unsigned short* pBsH = Bt + (size_t)(nBase + (wave << 4) + rl) * KK2 + cs;
  const unsigned short* pBsL = pBsH + NU;
  const int ldsA = wave << 11;                         // wave*2048 (A: 2 gl16)
  const int ldsB = wave << 10;                         // wave*1024 (B: 1 gl16)
  char* s0 = (char*)sL;
  char* s1 = s0 + 32768;
  char* s2 = s0 + 65536;
  char* s3 = s0 + 98304;

  // ---- fragment-read lane constants (R6-identical) ----
  const int pslot = (lk + ((lm >> 1) & 3)) & 3;
  const int aOff = (((wm << 6) + lm) << 6) + (pslot << 4);
  const int bOff = (((wn << 6) + lm) << 6) + (pslot << 4);

  f32x4 acc[4][4] = {};
  bf16x8 af[4], bh[4], bl[4];

  // prologue: stage iters 0,1,2 -> slabs 0,1,2; publish
  gl16(pAs, s0 + ldsA);           gl16(pAs2, s0 + ldsA + 1024);
  gl16(pBsH, s0 + 16384 + ldsB);  gl16(pBsL, s0 + 24576 + ldsB);
  gl16(pAs + 32, s1 + ldsA);          gl16(pAs2 + 32, s1 + ldsA + 1024);
  gl16(pBsH + 32, s1 + 16384 + ldsB); gl16(pBsL + 32, s1 + 24576 + ldsB);
  gl16(pAs + 64, s2 + ldsA);          gl16(pAs2 + 64, s2 + ldsA + 1024);
  gl16(pBsH + 64, s2 + 16384 + ldsB); gl16(pBsL + 64, s2 + 24576 + ldsB);
  VMW(0);
  BAR();

  for (int k = 0; k < NT; k += 4) {
    IT(k + 0, s0, s3);
    IT(k + 1, s1, s0);
    IT(k + 2, s2, s1);
    IT(k + 3, s3, s2);
  }

  // Fused sign epilogue. C/D layout (m89/m91): col=lane&15, row=(lane>>4)*4+reg
#pragma unroll
  for (int i = 0; i < 4; ++i)
#pragma unroll
    for (int j = 0; j < 4; ++j)
#pragma unroll
      for (int r = 0; r < 4; ++r) {
        const int row = mBase + (wm << 6) + i * 16 + (lk << 2) + r;
        const int col = nBase + (wn << 6) + j * 16 + lm;
        const float h = acc[i][j][r];
        Anext[(size_t)row * NU + col] =
            (h >= 0.0f) ? (unsigned short)0x3F80u : (unsigned short)0xBF80u;
        if (fabsf(h) < THETA) {
          int idx = atomicAdd(counter, 1);
          if (idx < CAP) suspects[idx] = (row << 12) | col;
        }
        if (writeOut)
          outF[(size_t)row * NU + col] = (h >= 0.0f) ? 1.0f : -1.0f;
      }
}

// Suspects, 8 lanes per suspect (one per KC=512 panel). Same sequential fp32
// chain as the round-8-verified version; bitwise-identical sign decision.
__global__ void fixup_kernel(const unsigned short* __restrict__ Acur,
                             const float* __restrict__ W,
                             unsigned short* __restrict__ Anext,
                             float* __restrict__ outF, int writeOut,
                             const int* __restrict__ counter,
                             const int* __restrict__ suspects,
                             int* __restrict__ flagOv) {
  int n = *counter;
  if (blockIdx.x == 0 && threadIdx.x == 0 && n > CAP) atomicAdd(flagOv, 1);
  n = n < CAP ? n : CAP;
  const int lane = threadIdx.x & 7;                       // panel index
  const int gid = (blockIdx.x * blockDim.x + threadIdx.x) >> 3;
  const int ngrp = (gridDim.x * blockDim.x) >> 3;
  for (int i = gid; i < n; i += ngrp) {
    int idx = suspects[i];
    int b = idx >> 12, j = idx & 4095;
    const float* wrow = W + (size_t)j * NU + lane * KC;
    const unsigned short* arow = Acur + (size_t)b * NU + lane * KC;
    float part = 0.0f;
    for (int k = 0; k < KC; k += 4) {
      float4 wv = *(const float4*)(wrow + k);
      ushort4 av = *(const ushort4*)(arow + k);
      part += (av.x & 0x8000) ? -wv.x : wv.x;
      part += (av.y & 0x8000) ? -wv.y : wv.y;
      part += (av.z & 0x8000) ? -wv.z : wv.z;
      part += (av.w & 0x8000) ? -wv.w : wv.w;
    }
    float c = __shfl(part, 0, 8);
#pragma unroll
    for (int q = 1; q < 8; ++q) c += __shfl(part, q, 8);
    if (lane == 0) {
      Anext[(size_t)b * NU + j] =
          (c >= 0.0f) ? (unsigned short)0x3F80u : (unsigned short)0xBF80u;
      if (writeOut) outF[(size_t)b * NU + j] = (c >= 0.0f) ? 1.0f : -1.0f;
    }
  }
}

// Tripwire: if the suspect list ever overflows, poison the output signature.
__global__ void assemble_kernel(float* __restrict__ out,
                                const int* __restrict__ flags) {
  if (threadIdx.x != 0 || blockIdx.x != 0) return;
  if (flags[1]) out[0] = 7777.0f;
}

extern "C" void kernel_launch(void* const* d_in, const int* in_sizes, int n_in,
                              void* d_out, int out_size, void* d_ws, size_t ws_size,
                              hipStream_t stream) {
  const float* P = (const float*)d_in[0];
  const float* W = (const float*)d_in[1];
  float* out = (float*)d_out;

  if (n_in < 2 || in_sizes[0] != NB * NU || in_sizes[1] != NU * NU ||
      out_size != NB * NU) {
    fill_kernel<<<4096, 256, 0, stream>>>(out, 9.0f);
    return;
  }
  if (ws_size < (size_t)REQ_WS) {
    fill_kernel<<<4096, 256, 0, stream>>>(out, 3.0f);
    return;
  }

  char* w = (char*)d_ws;
  unsigned short* Bt = (unsigned short*)(w + OFF_BT);
  unsigned short* A0 = (unsigned short*)(w + OFF_A0);
  unsigned short* A1 = (unsigned short*)(w + OFF_A1);
  int* suspects = (int*)(w + OFF_SUS);
  int* counters = (int*)(w + OFF_CNT);
  int* flags = counters + 128;  // [1]=suspect overflow

  hipMemsetAsync(counters, 0, 1024, stream);
  decompose_kernel<<<16384, 256, 0, stream>>>(W, Bt);
  init_kernel<<<4096, 256, 0, stream>>>(P, A0);

  for (int t = 0; t < ITERS; ++t) {
    unsigned short* Ain = (t & 1) ? A1 : A0;
    unsigned short* Aout = (t & 1) ? A0 : A1;
    int fin = (t == ITERS - 1) ? 1 : 0;
    gemm_fused_kernel<<<256, 512, 0, stream>>>(Ain, Bt, Aout, out, fin,
                                               &counters[t], suspects);
    fixup_kernel<<<256, 256, 0, stream>>>(Ain, W, Aout, out, fin,
                                          &counters[t], suspects, &flags[1]);
  }
  assemble_kernel<<<1, 64, 0, stream>>>(out, flags);
}

// Round 9
// 13460.156 us; speedup vs baseline: 1.0852x; 1.0546x over previous
//
#include <hip/hip_runtime.h>
#include <stdint.h>

#define NU 4096
#define NB 2048
#define KK2 8192
#define ITERS 100
#define CAP 262144
#define THETA 0.05f
#define KC 512              // host fixup k-panel (verified)

// ws layout (bytes) — unchanged
#define OFF_BT   0u
#define OFF_A0   67108864u
#define OFF_A1   83886080u
#define OFF_SUS  100663296u
#define OFF_CNT  102760448u
#define REQ_WS   102761472u

// GEMM geometry: BM=256 x BN=128, 512 thr (8 waves 4Mx2N, wave-tile 64x64),
// grid 8x32 = 256 = 1 block/CU. BK=32, 128 tiles; per tile cluster hi
// (af x Bhi) + lo (af x Blo) with A read/staged once.
// ROUND-9 CHANGE — instruction-granularity MFMA/ds_read interleave via
// sched_group_barrier. Diagnosis: waves are in-order; with reads placed
// after a 16-MFMA cluster, the wave cannot issue them until the matrix
// pipe accepted all MFMAs (~310-620 cyc), so LDS and MFMA pipes strictly
// alternate at cluster scale (all 5 prior structures: MfmaUtil 27-31%,
// dur == LDS-serial + MFMA-serial exactly). Fix: one scheduling region
// per tile = {4 gl16 stage(k+3), 12 ds_read prime(k+1), 32 MFMA(tile k)}
// shaped [4xVMEM][2xDS][10x(3 MFMA,1 DS)][2 MFMA]; compiler counted
// lgkmcnt (<=13) handles read->MFMA deps; NO lgkmcnt(0) in loop.
// 4 slabs x 32 KB (A 16K @0, Bh 8K @16384, Bl 8K @24576); stage 3 tiles
// ahead; counted vmcnt(4) at tile end (retires batch k+2, issued ~2 tiles
// ~4800 cyc earlier); tail k>=125 vmcnt(0). One s_barrier per tile.
// Ledgers: batch k+2 (4 gl16) retired end-of-k, published at k->k+1 BAR,
// primed during k+1 — reads always 1 full barrier after publish. Slab j:
// primed during j-1 (reads retire via counted lgkm before tile-j MFMAs ->
// before j's end BAR), restaged during j+1 (post-BAR) — no WAR window.
// SLOT SWIZZLE (R6-derived, measured 0 conflicts in R6+R8): logical 16B
// slot sl of row r at phys slot (sl+(r>>1))&3; inverse on global source
// col; ds_read pslot=(lk+((lm>>1)&3))&3.
#define NT 128

typedef float f32x4 __attribute__((ext_vector_type(4)));
typedef __bf16 bf16x8 __attribute__((ext_vector_type(8)));

__device__ __forceinline__ unsigned short f2bf(float x) {
  unsigned u = __float_as_uint(x);
  u += 0x7FFFu + ((u >> 16) & 1u);
  return (unsigned short)(u >> 16);
}
__device__ __forceinline__ float bf2f(unsigned short h) {
  return __uint_as_float(((unsigned)h) << 16);
}

__device__ __forceinline__ void gl16(const unsigned short* g, char* l) {
  __builtin_amdgcn_global_load_lds(
      (const __attribute__((address_space(1))) unsigned int*)g,
      (__attribute__((address_space(3))) unsigned int*)l, 16, 0, 0);
}

__global__ void fill_kernel(float* __restrict__ out, float v) {
  int t = blockIdx.x * blockDim.x + threadIdx.x;
  int base = t << 3;
  float4 a = make_float4(v, v, v, v);
  *(float4*)(out + base) = a;
  *(float4*)(out + base + 4) = a;
}

__global__ void decompose_kernel(const float* __restrict__ W,
                                 unsigned short* __restrict__ Bt) {
  int t = blockIdx.x * blockDim.x + threadIdx.x;
  int base = t << 2;
  int j = base >> 12;
  int k = base & 4095;
  float4 w = *(const float4*)(W + (size_t)j * NU + k);
  unsigned short h0 = f2bf(w.x), h1 = f2bf(w.y), h2 = f2bf(w.z), h3 = f2bf(w.w);
  ushort4 hi = make_ushort4(h0, h1, h2, h3);
  ushort4 lo = make_ushort4(f2bf(w.x - bf2f(h0)), f2bf(w.y - bf2f(h1)),
                            f2bf(w.z - bf2f(h2)), f2bf(w.w - bf2f(h3)));
  *(ushort4*)(Bt + (size_t)j * KK2 + k) = hi;
  *(ushort4*)(Bt + (size_t)j * KK2 + NU + k) = lo;
}

// Initial state: P (fp32 +-1, exact) -> A0 bf16 +-1.
__global__ void init_kernel(const float* __restrict__ P,
                            unsigned short* __restrict__ A0) {
  int t = blockIdx.x * blockDim.x + threadIdx.x;
  int base = t << 3;
  float4 a = *(const float4*)(P + base);
  float4 b = *(const float4*)(P + base + 4);
  float hv[8] = {a.x, a.y, a.z, a.w, b.x, b.y, b.z, b.w};
  uint4 pk;
  unsigned short s[8];
#pragma unroll
  for (int i = 0; i < 8; ++i)
    s[i] = (hv[i] >= 0.0f) ? (unsigned short)0x3F80u : (unsigned short)0xBF80u;
  pk.x = (unsigned)s[0] | ((unsigned)s[1] << 16);
  pk.y = (unsigned)s[2] | ((unsigned)s[3] << 16);
  pk.z = (unsigned)s[4] | ((unsigned)s[5] << 16);
  pk.w = (unsigned)s[6] | ((unsigned)s[7] << 16);
  *(uint4*)(A0 + base) = pk;
}

// ---- schedule primitives ----
#define SCB() __builtin_amdgcn_sched_barrier(0)
#define SGB(m, n) __builtin_amdgcn_sched_group_barrier((m), (n), 0)
#define BAR() do { __builtin_amdgcn_sched_barrier(0);          \
                   __builtin_amdgcn_s_barrier();               \
                   __builtin_amdgcn_sched_barrier(0); } while (0)
#define VMW(N) do { asm volatile("s_waitcnt vmcnt(" #N ")" ::: "memory"); \
                    __builtin_amdgcn_sched_barrier(0); } while (0)
#define MMX(AF, BF)                                                           \
  _Pragma("unroll") for (int i_ = 0; i_ < 4; ++i_)                            \
  _Pragma("unroll") for (int j_ = 0; j_ < 4; ++j_)                            \
    acc[i_][j_] = __builtin_amdgcn_mfma_f32_16x16x32_bf16(                    \
        AF[i_], BF[j_], acc[i_][j_], 0, 0, 0);
#define RD4S(DST, BASE) _Pragma("unroll")                                     \
  for (int q_ = 0; q_ < 4; ++q_)                                              \
    DST[q_] = *(const bf16x8*)((BASE) + q_ * 1024);

// One tile (BK=32): sP = prime-source slab ((k+1)&3), sS = stage-dest slab
// ((k+3)&3). CF* = this tile's fragments (primed during k-1); PF* = next
// tile's, read here. One scheduling region: the SGB list interleaves
// 3 MFMA : 1 ds_read so the LDS pipe drains under the MFMA issue stream.
// Guards depend only on k (block-uniform; barrier-safe).
#define TB(k, sP, sS, CFa, CFh, CFl, PFa, PFh, PFl)                           \
  {                                                                           \
    const int kS_ = ((k) + 3) << 5;                                           \
    if ((k) + 3 < NT) {                                                       \
      gl16(pAs + kS_, (sS) + ldsA);                                           \
      gl16(pAs2 + kS_, (sS) + ldsA + 1024);                                   \
      gl16(pBsH + kS_, (sS) + 16384 + ldsB);                                  \
      gl16(pBsL + kS_, (sS) + 24576 + ldsB);                                  \
    }                                                                         \
    if ((k) + 1 < NT) {                                                       \
      RD4S(PFa, (sP) + aOff);                                                 \
      RD4S(PFh, (sP) + 16384 + bOff);                                         \
      RD4S(PFl, (sP) + 24576 + bOff);                                         \
    }                                                                         \
    MMX(CFa, CFh);                                                            \
    MMX(CFa, CFl);                                                            \
    SGB(0x10, 4);                 /* 4 gl16 first (HBM headroom) */           \
    SGB(0x100, 2);                /* 2 reads head-start */                    \
    SGB(0x8, 3); SGB(0x100, 1);  SGB(0x8, 3); SGB(0x100, 1);                  \
    SGB(0x8, 3); SGB(0x100, 1);  SGB(0x8, 3); SGB(0x100, 1);                  \
    SGB(0x8, 3); SGB(0x100, 1);  SGB(0x8, 3); SGB(0x100, 1);                  \
    SGB(0x8, 3); SGB(0x100, 1);  SGB(0x8, 3); SGB(0x100, 1);                  \
    SGB(0x8, 3); SGB(0x100, 1);  SGB(0x8, 3); SGB(0x100, 1);                  \
    SGB(0x8, 2);                  /* 30+2 = 32 MFMA, 2+10 = 12 reads */       \
    SCB();                                                                    \
    if ((k) + 3 < NT) { VMW(4); } else { VMW(0); }                            \
    BAR();                                                                    \
  }

__global__ void __launch_bounds__(512, 1)
gemm_fused_kernel(const unsigned short* __restrict__ A,
                  const unsigned short* __restrict__ Bt,
                  unsigned short* __restrict__ Anext,
                  float* __restrict__ outF, int writeOut,
                  int* __restrict__ counter,
                  int* __restrict__ suspects) {
  __shared__ __align__(16) unsigned short sL[65536];   // 131072 B = 4 x 32KB
  const int tid = threadIdx.x;
  const int wave = tid >> 6, lane = tid & 63;
  const int lm = lane & 15, lk = lane >> 4;
  const int wm = wave >> 1, wn = wave & 1;             // 4M x 2N wave grid
  const int nt = blockIdx.x & 31, mt = blockIdx.x >> 5;
  const int mBase = mt << 8, nBase = nt << 7;

  // ---- staging lane constants (R8-identical; measured 0 conflicts) ----
  const int rl = lane >> 2;                            // 0..15 rows
  const int cs = ((((lane & 3) - ((lane >> 3) & 3)) & 3) << 3);  // elems
  const unsigned short* pAs = A + (size_t)(mBase + (wave << 5) + rl) * NU + cs;
  const unsigned short* pAs2 = pAs + (size_t)16 * NU;
  const unsigned short* pBsH = Bt + (size_t)(nBase + (wave << 4) + rl) * KK2 + cs;
  const unsigned short* pBsL = pBsH + NU;
  const int ldsA = wave << 11;                         // wave*2048 (A: 2 gl16)
  const int ldsB = wave << 10;                         // wave*1024 (B: 1 gl16)
  char* s0 = (char*)sL;
  char* s1 = s0 + 32768;
  char* s2 = s0 + 65536;
  char* s3 = s0 + 98304;

  // ---- fragment-read lane constants (R8-identical) ----
  const int pslot = (lk + ((lm >> 1) & 3)) & 3;
  const int aOff = (((wm << 6) + lm) << 6) + (pslot << 4);
  const int bOff = (((wn << 6) + lm) << 6) + (pslot << 4);

  f32x4 acc[4][4] = {};
  bf16x8 afA[4], bhA[4], blA[4], afB[4], bhB[4], blB[4];

  // prologue: stage tiles 0,1,2 -> slabs 0,1,2; publish; prime tile 0 (set A)
  gl16(pAs, s0 + ldsA);           gl16(pAs2, s0 + ldsA + 1024);
  gl16(pBsH, s0 + 16384 + ldsB);  gl16(pBsL, s0 + 24576 + ldsB);
  gl16(pAs + 32, s1 + ldsA);          gl16(pAs2 + 32, s1 + ldsA + 1024);
  gl16(pBsH + 32, s1 + 16384 + ldsB); gl16(pBsL + 32, s1 + 24576 + ldsB);
  gl16(pAs + 64, s2 + ldsA);          gl16(pAs2 + 64, s2 + ldsA + 1024);
  gl16(pBsH + 64, s2 + 16384 + ldsB); gl16(pBsL + 64, s2 + 24576 + ldsB);
  VMW(0);
  BAR();
  RD4S(afA, s0 + aOff);
  RD4S(bhA, s0 + 16384 + bOff);
  RD4S(blA, s0 + 24576 + bOff);
  SCB();

  for (int k = 0; k < NT; k += 4) {
    TB(k + 0, s1, s3, afA, bhA, blA, afB, bhB, blB);
    TB(k + 1, s2, s0, afB, bhB, blB, afA, bhA, blA);
    TB(k + 2, s3, s1, afA, bhA, blA, afB, bhB, blB);
    TB(k + 3, s0, s2, afB, bhB, blB, afA, bhA, blA);
  }

  // Fused sign epilogue. C/D layout (m89/m91): col=lane&15, row=(lane>>4)*4+reg
#pragma unroll
  for (int i = 0; i < 4; ++i)
#pragma unroll
    for (int j = 0; j < 4; ++j)
#pragma unroll
      for (int r = 0; r < 4; ++r) {
        const int row = mBase + (wm << 6) + i * 16 + (lk << 2) + r;
        const int col = nBase + (wn << 6) + j * 16 + lm;
        const float h = acc[i][j][r];
        Anext[(size_t)row * NU + col] =
            (h >= 0.0f) ? (unsigned short)0x3F80u : (unsigned short)0xBF80u;
        if (fabsf(h) < THETA) {
          int idx = atomicAdd(counter, 1);
          if (idx < CAP) suspects[idx] = (row << 12) | col;
        }
        if (writeOut)
          outF[(size_t)row * NU + col] = (h >= 0.0f) ? 1.0f : -1.0f;
      }
}

// Suspects, 8 lanes per suspect (one per KC=512 panel). Same sequential fp32
// chain as the round-8-verified version; bitwise-identical sign decision.
__global__ void fixup_kernel(const unsigned short* __restrict__ Acur,
                             const float* __restrict__ W,
                             unsigned short* __restrict__ Anext,
                             float* __restrict__ outF, int writeOut,
                             const int* __restrict__ counter,
                             const int* __restrict__ suspects,
                             int* __restrict__ flagOv) {
  int n = *counter;
  if (blockIdx.x == 0 && threadIdx.x == 0 && n > CAP) atomicAdd(flagOv, 1);
  n = n < CAP ? n : CAP;
  const int lane = threadIdx.x & 7;                       // panel index
  const int gid = (blockIdx.x * blockDim.x + threadIdx.x) >> 3;
  const int ngrp = (gridDim.x * blockDim.x) >> 3;
  for (int i = gid; i < n; i += ngrp) {
    int idx = suspects[i];
    int b = idx >> 12, j = idx & 4095;
    const float* wrow = W + (size_t)j * NU + lane * KC;
    const unsigned short* arow = Acur + (size_t)b * NU + lane * KC;
    float part = 0.0f;
    for (int k = 0; k < KC; k += 4) {
      float4 wv = *(const float4*)(wrow + k);
      ushort4 av = *(const ushort4*)(arow + k);
      part += (av.x & 0x8000) ? -wv.x : wv.x;
      part += (av.y & 0x8000) ? -wv.y : wv.y;
      part += (av.z & 0x8000) ? -wv.z : wv.z;
      part += (av.w & 0x8000) ? -wv.w : wv.w;
    }
    float c = __shfl(part, 0, 8);
#pragma unroll
    for (int q = 1; q < 8; ++q) c += __shfl(part, q, 8);
    if (lane == 0) {
      Anext[(size_t)b * NU + j] =
          (c >= 0.0f) ? (unsigned short)0x3F80u : (unsigned short)0xBF80u;
      if (writeOut) outF[(size_t)b * NU + j] = (c >= 0.0f) ? 1.0f : -1.0f;
    }
  }
}

// Tripwire: if the suspect list ever overflows, poison the output signature.
__global__ void assemble_kernel(float* __restrict__ out,
                                const int* __restrict__ flags) {
  if (threadIdx.x != 0 || blockIdx.x != 0) return;
  if (flags[1]) out[0] = 7777.0f;
}

extern "C" void kernel_launch(void* const* d_in, const int* in_sizes, int n_in,
                              void* d_out, int out_size, void* d_ws, size_t ws_size,
                              hipStream_t stream) {
  const float* P = (const float*)d_in[0];
  const float* W = (const float*)d_in[1];
  float* out = (float*)d_out;

  if (n_in < 2 || in_sizes[0] != NB * NU || in_sizes[1] != NU * NU ||
      out_size != NB * NU) {
    fill_kernel<<<4096, 256, 0, stream>>>(out, 9.0f);
    return;
  }
  if (ws_size < (size_t)REQ_WS) {
    fill_kernel<<<4096, 256, 0, stream>>>(out, 3.0f);
    return;
  }

  char* w = (char*)d_ws;
  unsigned short* Bt = (unsigned short*)(w + OFF_BT);
  unsigned short* A0 = (unsigned short*)(w + OFF_A0);
  unsigned short* A1 = (unsigned short*)(w + OFF_A1);
  int* suspects = (int*)(w + OFF_SUS);
  int* counters = (int*)(w + OFF_CNT);
  int* flags = counters + 128;  // [1]=suspect overflow

  hipMemsetAsync(counters, 0, 1024, stream);
  decompose_kernel<<<16384, 256, 0, stream>>>(W, Bt);
  init_kernel<<<4096, 256, 0, stream>>>(P, A0);

  for (int t = 0; t < ITERS; ++t) {
    unsigned short* Ain = (t & 1) ? A1 : A0;
    unsigned short* Aout = (t & 1) ? A0 : A1;
    int fin = (t == ITERS - 1) ? 1 : 0;
    gemm_fused_kernel<<<256, 512, 0, stream>>>(Ain, Bt, Aout, out, fin,
                                               &counters[t], suspects);
    fixup_kernel<<<256, 256, 0, stream>>>(Ain, W, Aout, out, fin,
                                          &counters[t], suspects, &flags[1]);
  }
  assemble_kernel<<<1, 64, 0, stream>>>(out, flags);
}

// Round 10
// 12273.496 us; speedup vs baseline: 1.1901x; 1.0967x over previous
//
#include <hip/hip_runtime.h>
#include <stdint.h>

#define NU 4096
#define NB 2048
#define KK2 8192            // i8 bytes per Bt column: 2 levels x 4096
#define ITERS 100
#define CAP 262144
#define THETA 0.05f
#define KC 512              // host fixup k-panel (verified)
#define S1 0.03937007874f   // 5/127 — level-1 quant step
#define S2 (S1 / 254.0f)    // level-2 step; range = S1/2 exactly

// ws layout (bytes) — offsets unchanged (i8 arrays are smaller; gaps unused)
#define OFF_BT   0u
#define OFF_A0   67108864u
#define OFF_A1   83886080u
#define OFF_SUS  100663296u
#define OFF_CNT  102760448u
#define REQ_WS   102761472u

// ROUND-10 — i8 two-level GEMM. Rationale: 6 schedules (R1..R9) all measure
// ~2250 cyc per bf16 BK=32 tile = LDS-serial + MFMA-serial, zero overlap,
// invariant under barriers/vmcnt depth/SGB. So shrink both serial terms:
// A = +-1 exact in i8; W = I1*S1 + I2*S2 (i8 planes). Residual <= S2/2 =>
// dot-error sigma ~2.9e-3, 17 sigma inside the THETA=0.05 exact-recompute
// net (fixup still uses f32 W). mfma_i32_16x16x64_i8 = 2x bf16 rate; i8
// halves every LDS/HBM byte. Serialized model: 64 tiles x ~2600 cyc ~= 69
// us/iter vs ~120 measured bf16.
// Geometry: BM=256 x BN=128, 512 thr (8 waves 4Mx2N, wave-tile 64x64),
// grid 8x32 = 256 = 1 block/CU. BK=64 i8 per tile (both levels) -> NT=64.
// Slab 32 KB: A 16K @0 (256 rows x 64 B), B1 8K @16384, B2 8K @24576 —
// row = 64 B exactly as R8/R9, so the MEASURED-ZERO-CONFLICT slot swizzle
// carries verbatim: logical 16B slot sl of row r at phys (sl+(r>>1))&3;
// inverse on global source; read pslot=(lk+((lm>>1)&3))&3.
// 4 slabs, stage 3 ahead, VMW(4) steady / VMW(0) tail (R8 ledger verbatim:
// end of tile k outstanding = {k+2: 4, k+3: 4}; VMW(4) retires k+2,
// published at k->k+1 BAR, primed during k+1, bl-read during k+2).
// Dual i32 acc (one per level); combine in epilogue: h = S1*d1 + S2*d2.
#define NT 64

typedef int i32x4 __attribute__((ext_vector_type(4)));

__device__ __forceinline__ void gl16(const void* g, void* l) {
  __builtin_amdgcn_global_load_lds(
      (const __attribute__((address_space(1))) unsigned int*)g,
      (__attribute__((address_space(3))) unsigned int*)l, 16, 0, 0);
}

__global__ void fill_kernel(float* __restrict__ out, float v) {
  int t = blockIdx.x * blockDim.x + threadIdx.x;
  int base = t << 3;
  float4 a = make_float4(v, v, v, v);
  *(float4*)(out + base) = a;
  *(float4*)(out + base + 4) = a;
}

__device__ __forceinline__ int q127(float x, float s) {
  int v = (int)rintf(x / s);
  return v < -127 ? -127 : (v > 127 ? 127 : v);
}

// W f32 -> two i8 planes: Bt[col*8192 + k] = I1, Bt[col*8192 + 4096 + k] = I2.
__global__ void decompose_kernel(const float* __restrict__ W,
                                 signed char* __restrict__ Bt) {
  int t = blockIdx.x * blockDim.x + threadIdx.x;
  int base = t << 2;
  int j = base >> 12;
  int k = base & 4095;
  float4 w = *(const float4*)(W + (size_t)j * NU + k);
  int a0 = q127(w.x, S1), a1 = q127(w.y, S1), a2 = q127(w.z, S1), a3 = q127(w.w, S1);
  float r0 = w.x - (float)a0 * S1, r1 = w.y - (float)a1 * S1;
  float r2 = w.z - (float)a2 * S1, r3 = w.w - (float)a3 * S1;
  int b0 = q127(r0, S2), b1 = q127(r1, S2), b2 = q127(r2, S2), b3 = q127(r3, S2);
  uchar4 p1 = make_uchar4((unsigned char)a0, (unsigned char)a1,
                          (unsigned char)a2, (unsigned char)a3);
  uchar4 p2 = make_uchar4((unsigned char)b0, (unsigned char)b1,
                          (unsigned char)b2, (unsigned char)b3);
  *(uchar4*)(Bt + (size_t)j * KK2 + k) = p1;
  *(uchar4*)(Bt + (size_t)j * KK2 + 4096 + k) = p2;
}

// Initial state: P (fp32 +-1, exact) -> A0 i8 +-1.
__global__ void init_kernel(const float* __restrict__ P,
                            signed char* __restrict__ A0) {
  int t = blockIdx.x * blockDim.x + threadIdx.x;
  int base = t << 3;
  float4 a = *(const float4*)(P + base);
  float4 b = *(const float4*)(P + base + 4);
  float hv[8] = {a.x, a.y, a.z, a.w, b.x, b.y, b.z, b.w};
  unsigned char s[8];
#pragma unroll
  for (int i = 0; i < 8; ++i) s[i] = (hv[i] >= 0.0f) ? 0x01u : 0xFFu;
  uint2 pk;
  pk.x = (unsigned)s[0] | ((unsigned)s[1] << 8) | ((unsigned)s[2] << 16) |
         ((unsigned)s[3] << 24);
  pk.y = (unsigned)s[4] | ((unsigned)s[5] << 8) | ((unsigned)s[6] << 16) |
         ((unsigned)s[7] << 24);
  *(uint2*)(A0 + base) = pk;
}

// ---- schedule primitives ----
#define SCB() __builtin_amdgcn_sched_barrier(0)
#define SGB(m, n) __builtin_amdgcn_sched_group_barrier((m), (n), 0)
#define BAR() do { __builtin_amdgcn_sched_barrier(0);          \
                   __builtin_amdgcn_s_barrier();               \
                   __builtin_amdgcn_sched_barrier(0); } while (0)
#define VMW(N) do { asm volatile("s_waitcnt vmcnt(" #N ")" ::: "memory"); \
                    __builtin_amdgcn_sched_barrier(0); } while (0)
#define MMX(AF, BF, ACC)                                                      \
  _Pragma("unroll") for (int i_ = 0; i_ < 4; ++i_)                            \
  _Pragma("unroll") for (int j_ = 0; j_ < 4; ++j_)                            \
    ACC[i_][j_] = __builtin_amdgcn_mfma_i32_16x16x64_i8(                      \
        AF[i_], BF[j_], ACC[i_][j_], 0, 0, 0);
#define RD4S(DST, BASE) _Pragma("unroll")                                     \
  for (int q_ = 0; q_ < 4; ++q_)                                              \
    DST[q_] = *(const i32x4*)((BASE) + q_ * 1024);

// One tile (BK=64 i8, both levels). sC = compute slab (k&3), sP = prime
// source ((k+1)&3), sS = stage dest ((k+3)&3). CF(a,h) primed during k-1;
// bl (level-2 B) read here from sC (consumed by cluster 2, counted lgkm).
// SGB shapes [4 VMEM][2 DS][(3 MFMA,1 DS)x10][2 MFMA]: 32 MFMA, 12 DS.
// Guards depend only on k (block-uniform).
#define TB(k, sC, sP, sS, CFa, CFh, PFa, PFh)                                 \
  {                                                                           \
    const int kS_ = ((k) + 3) << 6;                                           \
    RD4S(bl, (sC) + 24576 + bOff);                                            \
    if ((k) + 3 < NT) {                                                       \
      gl16(pAs + kS_, (sS) + ldsA);                                           \
      gl16(pAs2 + kS_, (sS) + ldsA + 1024);                                   \
      gl16(pBsH + kS_, (sS) + 16384 + ldsB);                                  \
      gl16(pBsL + kS_, (sS) + 24576 + ldsB);                                  \
    }                                                                         \
    if ((k) + 1 < NT) {                                                       \
      RD4S(PFa, (sP) + aOff);                                                 \
      RD4S(PFh, (sP) + 16384 + bOff);                                         \
    }                                                                         \
    MMX(CFa, CFh, acc1);                                                      \
    MMX(CFa, bl, acc2);                                                       \
    SGB(0x10, 4);                                                             \
    SGB(0x100, 2);                                                            \
    SGB(0x8, 3); SGB(0x100, 1);  SGB(0x8, 3); SGB(0x100, 1);                  \
    SGB(0x8, 3); SGB(0x100, 1);  SGB(0x8, 3); SGB(0x100, 1);                  \
    SGB(0x8, 3); SGB(0x100, 1);  SGB(0x8, 3); SGB(0x100, 1);                  \
    SGB(0x8, 3); SGB(0x100, 1);  SGB(0x8, 3); SGB(0x100, 1);                  \
    SGB(0x8, 3); SGB(0x100, 1);  SGB(0x8, 3); SGB(0x100, 1);                  \
    SGB(0x8, 2);                                                              \
    SCB();                                                                    \
    if ((k) + 3 < NT) { VMW(4); } else { VMW(0); }                            \
    BAR();                                                                    \
  }

__global__ void __launch_bounds__(512, 1)
gemm_fused_kernel(const signed char* __restrict__ A,
                  const signed char* __restrict__ Bt,
                  signed char* __restrict__ Anext,
                  float* __restrict__ outF, int writeOut,
                  int* __restrict__ counter,
                  int* __restrict__ suspects) {
  __shared__ __align__(16) unsigned char sL[131072];   // 4 x 32 KB slabs
  const int tid = threadIdx.x;
  const int wave = tid >> 6, lane = tid & 63;
  const int lm = lane & 15, lk = lane >> 4;
  const int wm = wave >> 1, wn = wave & 1;             // 4M x 2N wave grid
  const int nt = blockIdx.x & 31, mt = blockIdx.x >> 5;
  const int mBase = mt << 8, nBase = nt << 7;

  // ---- staging lane constants (swizzle congruences identical to R6/R8:
  // rows per gl16 chunk all == 0 mod 8 except rl; cs carries the inverse) --
  const int rl = lane >> 2;                            // 0..15 rows
  const int cs = ((((lane & 3) - ((lane >> 3) & 3)) & 3) << 4);  // i8 elems
  const signed char* pAs = A + (size_t)(mBase + (wave << 5) + rl) * NU + cs;
  const signed char* pAs2 = pAs + (size_t)16 * NU;
  const signed char* pBsH = Bt + (size_t)(nBase + (wave << 4) + rl) * KK2 + cs;
  const signed char* pBsL = pBsH + 4096;               // level-2 plane
  const int ldsA = wave << 11;                         // wave*2048 (A: 2 gl16)
  const int ldsB = wave << 10;                         // wave*1024 (B: 1 gl16)
  unsigned char* s0 = sL;
  unsigned char* s1 = s0 + 32768;
  unsigned char* s2 = s0 + 65536;
  unsigned char* s3 = s0 + 98304;

  // ---- fragment-read lane constants (64-B rows; verbatim R8) ----
  const int pslot = (lk + ((lm >> 1) & 3)) & 3;
  const int aOff = (((wm << 6) + lm) << 6) + (pslot << 4);
  const int bOff = (((wn << 6) + lm) << 6) + (pslot << 4);

  i32x4 acc1[4][4] = {};                               // level-1 acc
  i32x4 acc2[4][4] = {};                               // level-2 acc
  i32x4 afA[4], bhA[4], afB[4], bhB[4], bl[4];

  // prologue: stage tiles 0,1,2 -> slabs 0,1,2; publish; prime tile 0 (set A)
  gl16(pAs, s0 + ldsA);           gl16(pAs2, s0 + ldsA + 1024);
  gl16(pBsH, s0 + 16384 + ldsB);  gl16(pBsL, s0 + 24576 + ldsB);
  gl16(pAs + 64, s1 + ldsA);          gl16(pAs2 + 64, s1 + ldsA + 1024);
  gl16(pBsH + 64, s1 + 16384 + ldsB); gl16(pBsL + 64, s1 + 24576 + ldsB);
  gl16(pAs + 128, s2 + ldsA);          gl16(pAs2 + 128, s2 + ldsA + 1024);
  gl16(pBsH + 128, s2 + 16384 + ldsB); gl16(pBsL + 128, s2 + 24576 + ldsB);
  VMW(0);
  BAR();
  RD4S(afA, s0 + aOff);
  RD4S(bhA, s0 + 16384 + bOff);
  SCB();

  for (int k = 0; k < NT; k += 4) {
    TB(k + 0, s0, s1, s3, afA, bhA, afB, bhB);
    TB(k + 1, s1, s2, s0, afB, bhB, afA, bhA);
    TB(k + 2, s2, s3, s1, afA, bhA, afB, bhB);
    TB(k + 3, s3, s0, s2, afB, bhB, afA, bhA);
  }

  // Fused sign epilogue. C/D layout (m89/m91, dtype-independent m121-128):
  // col=lane&15, row=(lane>>4)*4+reg. h = S1*d1 + S2*d2.
#pragma unroll
  for (int i = 0; i < 4; ++i)
#pragma unroll
    for (int j = 0; j < 4; ++j)
#pragma unroll
      for (int r = 0; r < 4; ++r) {
        const int row = mBase + (wm << 6) + i * 16 + (lk << 2) + r;
        const int col = nBase + (wn << 6) + j * 16 + lm;
        const float h = S1 * (float)acc1[i][j][r] + S2 * (float)acc2[i][j][r];
        Anext[(size_t)row * NU + col] =
            (h >= 0.0f) ? (signed char)1 : (signed char)-1;
        if (fabsf(h) < THETA) {
          int idx = atomicAdd(counter, 1);
          if (idx < CAP) suspects[idx] = (row << 12) | col;
        }
        if (writeOut)
          outF[(size_t)row * NU + col] = (h >= 0.0f) ? 1.0f : -1.0f;
      }
}

// Suspects, 8 lanes per suspect (one per KC=512 panel). Sequential f32 chain
// against ORIGINAL f32 W — exact sign decision, unchanged math.
__global__ void fixup_kernel(const signed char* __restrict__ Acur,
                             const float* __restrict__ W,
                             signed char* __restrict__ Anext,
                             float* __restrict__ outF, int writeOut,
                             const int* __restrict__ counter,
                             const int* __restrict__ suspects,
                             int* __restrict__ flagOv) {
  int n = *counter;
  if (blockIdx.x == 0 && threadIdx.x == 0 && n > CAP) atomicAdd(flagOv, 1);
  n = n < CAP ? n : CAP;
  const int lane = threadIdx.x & 7;                       // panel index
  const int gid = (blockIdx.x * blockDim.x + threadIdx.x) >> 3;
  const int ngrp = (gridDim.x * blockDim.x) >> 3;
  for (int i = gid; i < n; i += ngrp) {
    int idx = suspects[i];
    int b = idx >> 12, j = idx & 4095;
    const float* wrow = W + (size_t)j * NU + lane * KC;
    const signed char* arow = Acur + (size_t)b * NU + lane * KC;
    float part = 0.0f;
    for (int k = 0; k < KC; k += 4) {
      float4 wv = *(const float4*)(wrow + k);
      unsigned av = *(const unsigned*)(arow + k);
      part += (av & 0x80u) ? -wv.x : wv.x;
      part += (av & 0x8000u) ? -wv.y : wv.y;
      part += (av & 0x800000u) ? -wv.z : wv.z;
      part += (av & 0x80000000u) ? -wv.w : wv.w;
    }
    float c = __shfl(part, 0, 8);
#pragma unroll
    for (int q = 1; q < 8; ++q) c += __shfl(part, q, 8);
    if (lane == 0) {
      Anext[(size_t)b * NU + j] = (c >= 0.0f) ? (signed char)1 : (signed char)-1;
      if (writeOut) outF[(size_t)b * NU + j] = (c >= 0.0f) ? 1.0f : -1.0f;
    }
  }
}

// Tripwire: if the suspect list ever overflows, poison the output signature.
__global__ void assemble_kernel(float* __restrict__ out,
                                const int* __restrict__ flags) {
  if (threadIdx.x != 0 || blockIdx.x != 0) return;
  if (flags[1]) out[0] = 7777.0f;
}

extern "C" void kernel_launch(void* const* d_in, const int* in_sizes, int n_in,
                              void* d_out, int out_size, void* d_ws, size_t ws_size,
                              hipStream_t stream) {
  const float* P = (const float*)d_in[0];
  const float* W = (const float*)d_in[1];
  float* out = (float*)d_out;

  if (n_in < 2 || in_sizes[0] != NB * NU || in_sizes[1] != NU * NU ||
      out_size != NB * NU) {
    fill_kernel<<<4096, 256, 0, stream>>>(out, 9.0f);
    return;
  }
  if (ws_size < (size_t)REQ_WS) {
    fill_kernel<<<4096, 256, 0, stream>>>(out, 3.0f);
    return;
  }

  char* w = (char*)d_ws;
  signed char* Bt = (signed char*)(w + OFF_BT);
  signed char* A0 = (signed char*)(w + OFF_A0);
  signed char* A1 = (signed char*)(w + OFF_A1);
  int* suspects = (int*)(w + OFF_SUS);
  int* counters = (int*)(w + OFF_CNT);
  int* flags = counters + 128;  // [1]=suspect overflow

  hipMemsetAsync(counters, 0, 1024, stream);
  decompose_kernel<<<16384, 256, 0, stream>>>(W, Bt);
  init_kernel<<<4096, 256, 0, stream>>>(P, A0);

  for (int t = 0; t < ITERS; ++t) {
    signed char* Ain = (t & 1) ? A1 : A0;
    signed char* Aout = (t & 1) ? A0 : A1;
    int fin = (t == ITERS - 1) ? 1 : 0;
    gemm_fused_kernel<<<256, 512, 0, stream>>>(Ain, Bt, Aout, out, fin,
                                               &counters[t], suspects);
    fixup_kernel<<<256, 256, 0, stream>>>(Ain, W, Aout, out, fin,
                                          &counters[t], suspects, &flags[1]);
  }
  assemble_kernel<<<1, 64, 0, stream>>>(out, flags);
}